// Round 6
// baseline (161.101 us; speedup 1.0000x reference)
//
#include <hip/hip_runtime.h>
#include <hip/hip_bf16.h>
#include <math.h>

// Problem constants (B,C,H,W,O,K,E) = (8,256,64,64,256,3,3)
// weff[b,o,c,tap] = sum_e gates[b,e]*(experts[e,o,c,tap]+experts[e,o,c+256,tap])
// out[b,o,h,w] = sum_{c,dh,dw} q[b,c,h+dh-1,w+dw-1] * weff[b,o,c,dh*3+dw]
//
// Workspace layout (~27.3 MB):
//   [0)        yctx   : 2048 f32
//   [16384)    wf     : bf16, per (b,tap,ch) 16KB slab; element (o,c) at byte
//                       (o>>4)*1024 + ((c&31)>>3)*256 + (o&15)*16 + (c&7)*2
//                       => conv wave A-load is IDENTITY-ORDER contiguous 1KB
//   [9453568)  qT     : bf16 [8 b][8 ch][66 hp][66 wp][32 cl']   (17,842,176 B)
// qT cl' swizzle: group' = (cl>>3) ^ ((wp>>1)&3); keeps ds_read_b128 B-fragment
// reads at free 2-way bank conflicts.
//
// R6: qt-store fix (same mechanism as R4 conv-A win and R5 wbuild-store win):
// old qt wrote 8B chunks at swizzled addresses (64B lines covered by 8 permuted
// lane-fragments). New qt inverts the swizzle on the LDS-read side: each lane
// serves one LINEAR 16B destination chunk, gathering source group g'^((wp>>1)&3)
// from the LDS tile. Stores are identity-order 16B over contiguous 4224B runs.
// Re-blocked to 512 blocks x 8 h-rows, double-buffered LDS. qT bytes identical.
// conv/yctx/wbuild untouched.

typedef __bf16 bf16x8 __attribute__((ext_vector_type(8)));
typedef __bf16 bf16x4 __attribute__((ext_vector_type(4)));
typedef float f32x4 __attribute__((ext_vector_type(4)));

#define AS1 __attribute__((address_space(1)))
#define AS3 __attribute__((address_space(3)))

// ---------------- kernel 1: y_ctx[b,c] = mean_{h,w} y ----------------
__global__ __launch_bounds__(256) void yctx_kernel(const float* __restrict__ y,
                                                   float* __restrict__ yctx) {
  int bc = blockIdx.x;  // b*256 + c
  const float4* p = (const float4*)(y + (size_t)bc * 4096);
  int tid = threadIdx.x;
  float s = 0.f;
#pragma unroll
  for (int k = 0; k < 4; k++) {
    float4 v = p[tid + k * 256];
    s += v.x + v.y + v.z + v.w;
  }
#pragma unroll
  for (int off = 32; off > 0; off >>= 1) s += __shfl_down(s, off, 64);
  __shared__ float wsum[4];
  if ((tid & 63) == 0) wsum[tid >> 6] = s;
  __syncthreads();
  if (tid == 0) yctx[bc] = (wsum[0] + wsum[1] + wsum[2] + wsum[3]) * (1.f / 4096.f);
}

// ---------------- kernel 2: prep = wbuild (blocks 0..255) + qt (blocks 256..767) ----------------
union PrepSmem {
  struct {
    float sfold[3 * 16 * 145];  // folded experts [e*16+ol][cloc*9+tap], stride 145 (27.8 KB)
    float lg[8][3];
    float g[8][3];
  } wb;
  float t2[2][64][33];          // qt transpose tile, double-buffered (16.9 KB)
};

__global__ __launch_bounds__(256) void prep_kernel(const float* __restrict__ q,
                                                   const float* __restrict__ experts,
                                                   const float* __restrict__ yctx,
                                                   const float* __restrict__ gw,
                                                   const float* __restrict__ gb,
                                                   __bf16* __restrict__ qT,
                                                   __bf16* __restrict__ wf) {
  __shared__ PrepSmem sm;
  int bid = blockIdx.x;
  int tid = threadIdx.x;

  if (bid < 256) {
    // ======== wbuild role: block = (og, chh); o in [og*16, og*16+16), c in [chh*16, chh*16+16) ========
    int og = bid >> 4, chh = bid & 15;
    int chb = chh >> 1;          // 32-c slab index (c>>5)
    int qb = (chh & 1) * 2;      // c-oct base within slab (0 or 2)

    // logits: 8 b-groups of 32 lanes; each lane covers 8 c's for all 3 e
    {
      int lb = tid >> 5, li = tid & 31;
      float p0 = 0.f, p1 = 0.f, p2 = 0.f;
#pragma unroll
      for (int j = 0; j < 8; j++) {
        int c = li + j * 32;
        float yv = yctx[lb * 256 + c];
        p0 += yv * (gw[c * 3 + 0] + gw[(c + 256) * 3 + 0]);
        p1 += yv * (gw[c * 3 + 1] + gw[(c + 256) * 3 + 1]);
        p2 += yv * (gw[c * 3 + 2] + gw[(c + 256) * 3 + 2]);
      }
#pragma unroll
      for (int off = 16; off > 0; off >>= 1) {
        p0 += __shfl_down(p0, off, 32);
        p1 += __shfl_down(p1, off, 32);
        p2 += __shfl_down(p2, off, 32);
      }
      if (li == 0) {
        sm.wb.lg[lb][0] = p0 + gb[0];
        sm.wb.lg[lb][1] = p1 + gb[1];
        sm.wb.lg[lb][2] = p2 + gb[2];
      }
    }

    // stage folded experts: 48 (e,o) pairs x 36 float4 (lo) + 36 (hi), fold-add
    for (int i = tid; i < 1728; i += 256) {
      int p = i / 36, f = i - p * 36;   // p = e*16 + olp
      int e = p >> 4, olp = p & 15;
      int o = og * 16 + olp;
      const float4* src = (const float4*)experts + ((size_t)(e * 256 + o)) * 1152 + chh * 36;
      float4 lo = src[f], hi = src[f + 576];
      float* dst = &sm.wb.sfold[p * 145 + f * 4];
      dst[0] = lo.x + hi.x; dst[1] = lo.y + hi.y;
      dst[2] = lo.z + hi.z; dst[3] = lo.w + hi.w;
    }
    __syncthreads();
    if (tid < 8) {
      float l0 = sm.wb.lg[tid][0], l1 = sm.wb.lg[tid][1], l2 = sm.wb.lg[tid][2];
      float m = fmaxf(l0, fmaxf(l1, l2));
      float e0 = __expf(l0 - m), e1 = __expf(l1 - m), e2 = __expf(l2 - m);
      float inv = 1.f / (e0 + e1 + e2);
      sm.wb.g[tid][0] = e0 * inv; sm.wb.g[tid][1] = e1 * inv; sm.wb.g[tid][2] = e2 * inv;
    }
    __syncthreads();

    // mix + store: per b, 288 chunk-tasks (9 tap x 32 chunks); chunk = qdl*16+ol;
    // lane-consecutive chunks => contiguous 512B wf segments per half-wave.
#pragma unroll 1
    for (int b = 0; b < 8; b++) {
      float g0 = sm.wb.g[b][0], g1 = sm.wb.g[b][1], g2 = sm.wb.g[b][2];
      for (int i = tid; i < 288; i += 256) {
        int tap = i >> 5, ck = i & 31;
        int qdl = ck >> 4, ol = ck & 15;
        const float* r0 = &sm.wb.sfold[(0 * 16 + ol) * 145 + (qdl * 8) * 9 + tap];
        const float* r1 = &sm.wb.sfold[(1 * 16 + ol) * 145 + (qdl * 8) * 9 + tap];
        const float* r2 = &sm.wb.sfold[(2 * 16 + ol) * 145 + (qdl * 8) * 9 + tap];
        bf16x8 rv;
#pragma unroll
        for (int j = 0; j < 8; j++) {
          float v = g0 * r0[j * 9] + g1 * r1[j * 9] + g2 * r2[j * 9];
          rv[j] = (__bf16)v;
        }
        size_t byteoff = (((size_t)b * 9 + tap) * 8 + chb) * 16384 +
                         (size_t)og * 1024 + (size_t)(qb + qdl) * 256 + (size_t)ol * 16;
        *(bf16x8*)((char*)wf + byteoff) = rv;
      }
    }
    return;
  }

  // ======== qt role: blocks 256..767 = (b, ch, hg); 8 h-rows per block ========
  {
    int qb2 = bid - 256;
    int hg = qb2 & 7;
    int t2i = qb2 >> 3;
    int ch = t2i & 7;
    int b = t2i >> 3;
    __bf16* dstbase = qT + ((size_t)(b * 8 + ch) * 66) * 66 * 32;  // hp stride: 2112 bf16
    const float* qsrc = q + ((size_t)b * 256 + ch * 32) * 4096;    // [c][h][w]

    int w = tid & 63, ci = tid >> 6;
    int h0r = hg * 8;
    // prologue: load h0r into buf 0
#pragma unroll
    for (int j = 0; j < 8; j++) {
      int c = ci * 8 + j;
      sm.t2[0][w][c] = qsrc[((size_t)c * 64 + h0r) * 64 + w];
    }
    __syncthreads();

#pragma unroll 1
    for (int r = 0; r < 8; r++) {
      // issue next-row loads into regs (overlaps the store phase)
      float nxt[8];
      if (r < 7) {
        int h = h0r + r + 1;
#pragma unroll
        for (int j = 0; j < 8; j++) {
          int c = ci * 8 + j;
          nxt[j] = qsrc[((size_t)c * 64 + h) * 64 + w];
        }
      }
      // store phase for row r (hp = h0r+r+1): identity-order 16B chunks over
      // the contiguous 4224B row; swizzle inverted on the LDS-read side.
      int hp = h0r + r + 1;
      char* dst = (char*)(dstbase + (size_t)hp * 2112);
      const float (*tcur)[33] = sm.t2[r & 1];
      for (int m = tid; m < 264; m += 256) {
        int wp = m >> 2, gp = m & 3;
        bf16x8 rv;
        if (wp == 0 || wp == 65) {
#pragma unroll
          for (int j = 0; j < 8; j++) rv[j] = (__bf16)0.f;
        } else {
          int gsrc = gp ^ ((wp >> 1) & 3);
          const float* s = &tcur[wp - 1][gsrc * 8];
#pragma unroll
          for (int j = 0; j < 8; j++) rv[j] = (__bf16)s[j];
        }
        *(bf16x8*)(dst + m * 16) = rv;
      }
      // stage next row into the other buffer
      if (r < 7) {
#pragma unroll
        for (int j = 0; j < 8; j++) {
          int c = ci * 8 + j;
          sm.t2[(r + 1) & 1][w][c] = nxt[j];
        }
      }
      __syncthreads();
    }
    // edge padding rows hp=0 (hg==0) / hp=65 (hg==7)
    if (hg == 0 || hg == 7) {
      int hp = (hg == 0) ? 0 : 65;
      float4* dz = (float4*)(dstbase + (size_t)hp * 2112);
      float4 z4 = {0.f, 0.f, 0.f, 0.f};
      for (int i = tid; i < 264; i += 256) dz[i] = z4;
    }
  }
}

// ---------------- kernel 3: MFMA conv — 4-h blocks, identity-order A loads (R4, proven) ----------------
__global__ __launch_bounds__(512, 2) void conv_kernel(const __bf16* __restrict__ qT,
                                                      const __bf16* __restrict__ wf,
                                                      float* __restrict__ out) {
  __shared__ __align__(16) __bf16 Qlds[2][6 * 66 * 32];  // 2 x 25,344 B = 50.7 KB
  const int tid = threadIdx.x;
  const int lane = tid & 63;
  const int wv = tid >> 6;        // 0..7
  const int wm = wv >> 2;         // o half (0/1)
  const int wn = wv & 3;          // h row within block (0..3)
  const int l15 = lane & 15, qd = lane >> 4;

  const int bid = blockIdx.x;
  const int b = bid & 7;          // XCD swizzle: b's wf+qT (~3.4MB) pinned to one XCD L2
  const int rem = bid >> 3;       // 0..31
  const int o0 = (rem >> 4) * 128;
  const int hq = (rem & 15) * 4;  // 4 output rows per block

  f32x4 acc[4][4];
  {
    f32x4 z = {0.f, 0.f, 0.f, 0.f};
#pragma unroll
    for (int i = 0; i < 4; i++)
#pragma unroll
      for (int j = 0; j < 4; j++) acc[i][j] = z;
  }

  const char* qT_b = (const char*)qT + (size_t)b * 8 * 66 * 66 * 32 * 2;
  // A-fragment base, identity-order layout: lane reads 16 B at
  //   (o0+wm*64)*64 + lane*16  (+ mi*1024 per mi, + (tap*8+ch)*16384 per step)
  const char* abase = (const char*)wf + (size_t)b * 9 * 8 * 16384 +
                      (size_t)(o0 + wm * 64) * 64 + (size_t)lane * 16;
  // 3-phase A register rotation: tap t consumes areg[t%3], issues A(t+2).
  bf16x8 areg[3][4];

  // ---- prologue: stage Q(ch=0) rows hq..hq+5 -> Qlds[0]; load A(0), A(1)
  {
    const char* qsrc = qT_b + ((size_t)hq) * 66 * 32 * 2;
    for (int i = tid; i < 1584; i += 512) {
      int ub = i - lane;
      __builtin_amdgcn_global_load_lds((const AS1 void*)(qsrc + ((size_t)i << 4)),
                                       (AS3 void*)((char*)Qlds[0] + ((size_t)ub << 4)),
                                       16, 0, 0);
    }
#pragma unroll
    for (int mi = 0; mi < 4; mi++) {
      areg[0][mi] = *(const bf16x8*)(abase + mi * 1024);                      // (tap0,ch0)
      areg[1][mi] = *(const bf16x8*)(abase + ((size_t)8 << 14) + mi * 1024);  // (tap1,ch0)
    }
    __syncthreads();  // drain Q0 staging
  }

#pragma unroll 1
  for (int ch = 0; ch < 8; ch++) {
    const char* Qb = (const char*)Qlds[ch & 1];
    const char* qsrc_n = qT_b + ((size_t)(ch + 1) * 66 + hq) * 66 * 32 * 2;
    char* qdst_n = (char*)Qlds[(ch + 1) & 1];
#pragma unroll
    for (int tap = 0; tap < 9; tap++) {
      // 1) issue A(t+2) first (ahead of Q issues this tap)
      {
        int tapn = (tap + 2 >= 9) ? tap - 7 : tap + 2;
        int chn = (tap + 2 >= 9) ? ch + 1 : ch;  // chn==8 on last ch: in-bounds garbage, unused
        size_t aoff = ((size_t)(tapn * 8 + chn)) << 14;
#pragma unroll
        for (int mi = 0; mi < 4; mi++)
          areg[(tap + 2) % 3][mi] = *(const bf16x8*)(abase + aoff + mi * 1024);
      }
      // 2) Q staging for ch+1, two halves at tap0/tap1
      if (ch < 7) {
        if (tap == 0) {
          for (int i = tid; i < 792; i += 512) {
            int ub = i - lane;
            __builtin_amdgcn_global_load_lds((const AS1 void*)(qsrc_n + ((size_t)i << 4)),
                                             (AS3 void*)(qdst_n + ((size_t)ub << 4)),
                                             16, 0, 0);
          }
        } else if (tap == 1) {
          for (int i = 792 + tid; i < 1584; i += 512) {
            int ub = i - lane;
            __builtin_amdgcn_global_load_lds((const AS1 void*)(qsrc_n + ((size_t)i << 4)),
                                             (AS3 void*)(qdst_n + ((size_t)ub << 4)),
                                             16, 0, 0);
          }
        }
      }
      // 3) compute with areg[tap%3]
      const int dh = tap / 3, dw = tap - dh * 3;
      const int r = wn + dh;  // 0..5
#pragma unroll
      for (int ni = 0; ni < 4; ni++) {
        int wp = ni * 16 + l15 + dw;  // 0..65
        int g = (qd ^ ((wp >> 1) & 3)) << 3;
        bf16x8 bfv = *(const bf16x8*)(Qb + ((r * 66 + wp) * 32 + g) * 2);
#pragma unroll
        for (int mi = 0; mi < 4; mi++)
          acc[mi][ni] = __builtin_amdgcn_mfma_f32_16x16x32_bf16(
              areg[tap % 3][mi], bfv, acc[mi][ni], 0, 0, 0);
      }
    }
    __syncthreads();  // end of ch: Q(ch+1) staged+drained; buffer reuse safe
  }

  // epilogue: C/D layout col = lane&15 (w), row = qd*4+rr (o)
  const int hh = hq + wn;
#pragma unroll
  for (int mi = 0; mi < 4; mi++) {
    int o = o0 + wm * 64 + mi * 16 + qd * 4;
#pragma unroll
    for (int ni = 0; ni < 4; ni++) {
      int w = ni * 16 + l15;
#pragma unroll
      for (int rr = 0; rr < 4; rr++)
        out[(((size_t)b * 256 + (o + rr)) * 64 + hh) * 64 + w] = acc[mi][ni][rr];
    }
  }
}

extern "C" void kernel_launch(void* const* d_in, const int* in_sizes, int n_in,
                              void* d_out, int out_size, void* d_ws, size_t ws_size,
                              hipStream_t stream) {
  (void)in_sizes; (void)n_in; (void)out_size; (void)ws_size;
  const float* q = (const float*)d_in[0];
  const float* y = (const float*)d_in[1];
  const float* experts = (const float*)d_in[2];
  const float* gate_w = (const float*)d_in[3];
  const float* gate_b = (const float*)d_in[4];
  float* out = (float*)d_out;

  char* ws = (char*)d_ws;
  float* yctx = (float*)ws;                         // 8 KB
  __bf16* wf = (__bf16*)(ws + 16384);               // 9,437,184 B
  __bf16* qT = (__bf16*)(ws + 16384 + 9437184);     // 17,842,176 B

  yctx_kernel<<<2048, 256, 0, stream>>>(y, yctx);
  prep_kernel<<<256 + 512, 256, 0, stream>>>(q, experts, yctx, gate_w, gate_b, qT, wf);
  conv_kernel<<<256, 512, 0, stream>>>(qT, wf, out);
}

// Round 7
// 158.725 us; speedup vs baseline: 1.0150x; 1.0150x over previous
//
#include <hip/hip_runtime.h>
#include <hip/hip_bf16.h>
#include <math.h>

// Problem constants (B,C,H,W,O,K,E) = (8,256,64,64,256,3,3)
// weff[b,o,c,tap] = sum_e gates[b,e]*(experts[e,o,c,tap]+experts[e,o,c+256,tap])
// out[b,o,h,w] = sum_{c,dh,dw} q[b,c,h+dh-1,w+dw-1] * weff[b,o,c,dh*3+dw]
//
// Workspace layout (~27.3 MB):
//   [0)        yctx   : 2048 f32
//   [16384)    wf     : bf16, per (b,tap,ch) 16KB slab; element (o,c) at byte
//                       (o>>4)*1024 + ((c&31)>>3)*256 + (o&15)*16 + (c&7)*2
//                       => conv wave A-load is IDENTITY-ORDER contiguous 1KB
//   [9453568)  qT     : bf16 [8 b][8 ch][66 hp][66 wp][32 cl']   (17,842,176 B)
// qT cl' swizzle: group' = (cl>>3) ^ ((wp>>1)&3); keeps ds_read_b128 B-fragment
// reads at free 2-way bank conflicts.
//
// R7: conv T4 (counted vmcnt). __syncthreads at each ch forced s_waitcnt
// vmcnt(0) — draining the Q DMA AND the A prefetch pipeline once per ch (the
// documented ~20% structural stall of the 2-barrier MFMA loop). At the ch
// boundary the 8 newest outstanding VMEM ops per wave are exactly the two
// next-ch A-prefetch batches; everything older is this ch's Q DMA. So:
//   s_waitcnt vmcnt(8) lgkmcnt(0) ; sched_barrier ; s_barrier ; sched_barrier
// keeps A in flight across the barrier, drains Q (per-wave => buffer complete
// after barrier). Numerics identical. Aux: qt loads now float4 (4x fewer
// load instructions). X-floor (~90us of total) believed to be harness-timed
// reset cost — not addressable from kernel code.

typedef __bf16 bf16x8 __attribute__((ext_vector_type(8)));
typedef __bf16 bf16x4 __attribute__((ext_vector_type(4)));
typedef float f32x4 __attribute__((ext_vector_type(4)));

#define AS1 __attribute__((address_space(1)))
#define AS3 __attribute__((address_space(3)))

// ---------------- kernel 1: y_ctx[b,c] = mean_{h,w} y ----------------
__global__ __launch_bounds__(256) void yctx_kernel(const float* __restrict__ y,
                                                   float* __restrict__ yctx) {
  int bc = blockIdx.x;  // b*256 + c
  const float4* p = (const float4*)(y + (size_t)bc * 4096);
  int tid = threadIdx.x;
  float s = 0.f;
#pragma unroll
  for (int k = 0; k < 4; k++) {
    float4 v = p[tid + k * 256];
    s += v.x + v.y + v.z + v.w;
  }
#pragma unroll
  for (int off = 32; off > 0; off >>= 1) s += __shfl_down(s, off, 64);
  __shared__ float wsum[4];
  if ((tid & 63) == 0) wsum[tid >> 6] = s;
  __syncthreads();
  if (tid == 0) yctx[bc] = (wsum[0] + wsum[1] + wsum[2] + wsum[3]) * (1.f / 4096.f);
}

// ---------------- kernel 2: prep = wbuild (blocks 0..255) + qt (blocks 256..767) ----------------
union PrepSmem {
  struct {
    float sfold[3 * 16 * 145];  // folded experts [e*16+ol][cloc*9+tap], stride 145 (27.8 KB)
    float lg[8][3];
    float g[8][3];
  } wb;
  float t2[2][64][33];          // qt transpose tile, double-buffered (16.9 KB)
};

__global__ __launch_bounds__(256) void prep_kernel(const float* __restrict__ q,
                                                   const float* __restrict__ experts,
                                                   const float* __restrict__ yctx,
                                                   const float* __restrict__ gw,
                                                   const float* __restrict__ gb,
                                                   __bf16* __restrict__ qT,
                                                   __bf16* __restrict__ wf) {
  __shared__ PrepSmem sm;
  int bid = blockIdx.x;
  int tid = threadIdx.x;

  if (bid < 256) {
    // ======== wbuild role: block = (og, chh); o in [og*16, og*16+16), c in [chh*16, chh*16+16) ========
    int og = bid >> 4, chh = bid & 15;
    int chb = chh >> 1;          // 32-c slab index (c>>5)
    int qb = (chh & 1) * 2;      // c-oct base within slab (0 or 2)

    // logits: 8 b-groups of 32 lanes; each lane covers 8 c's for all 3 e
    {
      int lb = tid >> 5, li = tid & 31;
      float p0 = 0.f, p1 = 0.f, p2 = 0.f;
#pragma unroll
      for (int j = 0; j < 8; j++) {
        int c = li + j * 32;
        float yv = yctx[lb * 256 + c];
        p0 += yv * (gw[c * 3 + 0] + gw[(c + 256) * 3 + 0]);
        p1 += yv * (gw[c * 3 + 1] + gw[(c + 256) * 3 + 1]);
        p2 += yv * (gw[c * 3 + 2] + gw[(c + 256) * 3 + 2]);
      }
#pragma unroll
      for (int off = 16; off > 0; off >>= 1) {
        p0 += __shfl_down(p0, off, 32);
        p1 += __shfl_down(p1, off, 32);
        p2 += __shfl_down(p2, off, 32);
      }
      if (li == 0) {
        sm.wb.lg[lb][0] = p0 + gb[0];
        sm.wb.lg[lb][1] = p1 + gb[1];
        sm.wb.lg[lb][2] = p2 + gb[2];
      }
    }

    // stage folded experts: 48 (e,o) pairs x 36 float4 (lo) + 36 (hi), fold-add
    for (int i = tid; i < 1728; i += 256) {
      int p = i / 36, f = i - p * 36;   // p = e*16 + olp
      int e = p >> 4, olp = p & 15;
      int o = og * 16 + olp;
      const float4* src = (const float4*)experts + ((size_t)(e * 256 + o)) * 1152 + chh * 36;
      float4 lo = src[f], hi = src[f + 576];
      float* dst = &sm.wb.sfold[p * 145 + f * 4];
      dst[0] = lo.x + hi.x; dst[1] = lo.y + hi.y;
      dst[2] = lo.z + hi.z; dst[3] = lo.w + hi.w;
    }
    __syncthreads();
    if (tid < 8) {
      float l0 = sm.wb.lg[tid][0], l1 = sm.wb.lg[tid][1], l2 = sm.wb.lg[tid][2];
      float m = fmaxf(l0, fmaxf(l1, l2));
      float e0 = __expf(l0 - m), e1 = __expf(l1 - m), e2 = __expf(l2 - m);
      float inv = 1.f / (e0 + e1 + e2);
      sm.wb.g[tid][0] = e0 * inv; sm.wb.g[tid][1] = e1 * inv; sm.wb.g[tid][2] = e2 * inv;
    }
    __syncthreads();

    // mix + store: per b, 288 chunk-tasks (9 tap x 32 chunks); chunk = qdl*16+ol;
    // lane-consecutive chunks => contiguous 512B wf segments per half-wave.
#pragma unroll 1
    for (int b = 0; b < 8; b++) {
      float g0 = sm.wb.g[b][0], g1 = sm.wb.g[b][1], g2 = sm.wb.g[b][2];
      for (int i = tid; i < 288; i += 256) {
        int tap = i >> 5, ck = i & 31;
        int qdl = ck >> 4, ol = ck & 15;
        const float* r0 = &sm.wb.sfold[(0 * 16 + ol) * 145 + (qdl * 8) * 9 + tap];
        const float* r1 = &sm.wb.sfold[(1 * 16 + ol) * 145 + (qdl * 8) * 9 + tap];
        const float* r2 = &sm.wb.sfold[(2 * 16 + ol) * 145 + (qdl * 8) * 9 + tap];
        bf16x8 rv;
#pragma unroll
        for (int j = 0; j < 8; j++) {
          float v = g0 * r0[j * 9] + g1 * r1[j * 9] + g2 * r2[j * 9];
          rv[j] = (__bf16)v;
        }
        size_t byteoff = (((size_t)b * 9 + tap) * 8 + chb) * 16384 +
                         (size_t)og * 1024 + (size_t)(qb + qdl) * 256 + (size_t)ol * 16;
        *(bf16x8*)((char*)wf + byteoff) = rv;
      }
    }
    return;
  }

  // ======== qt role: blocks 256..767 = (b, ch, hg); 8 h-rows per block ========
  {
    int qb2 = bid - 256;
    int hg = qb2 & 7;
    int t2i = qb2 >> 3;
    int ch = t2i & 7;
    int b = t2i >> 3;
    __bf16* dstbase = qT + ((size_t)(b * 8 + ch) * 66) * 66 * 32;  // hp stride: 2112 bf16
    const float4* qsrc4 = (const float4*)(q + ((size_t)b * 256 + ch * 32) * 4096);
    // qsrc4 index: (c*64 + h)*16 + w4

    int w4 = tid & 15, c0 = tid >> 4;  // tasks: (c0, w4) and (c0+16, w4)
    int h0r = hg * 8;
    // prologue: load row h0r into buf 0 (2 float4 per thread)
    {
      float4 a0 = qsrc4[((size_t)c0 * 64 + h0r) * 16 + w4];
      float4 a1 = qsrc4[((size_t)(c0 + 16) * 64 + h0r) * 16 + w4];
      sm.t2[0][w4 * 4 + 0][c0] = a0.x; sm.t2[0][w4 * 4 + 1][c0] = a0.y;
      sm.t2[0][w4 * 4 + 2][c0] = a0.z; sm.t2[0][w4 * 4 + 3][c0] = a0.w;
      sm.t2[0][w4 * 4 + 0][c0 + 16] = a1.x; sm.t2[0][w4 * 4 + 1][c0 + 16] = a1.y;
      sm.t2[0][w4 * 4 + 2][c0 + 16] = a1.z; sm.t2[0][w4 * 4 + 3][c0 + 16] = a1.w;
    }
    __syncthreads();

#pragma unroll 1
    for (int r = 0; r < 8; r++) {
      // issue next-row loads into regs (overlaps the store phase)
      float4 n0, n1;
      if (r < 7) {
        int h = h0r + r + 1;
        n0 = qsrc4[((size_t)c0 * 64 + h) * 16 + w4];
        n1 = qsrc4[((size_t)(c0 + 16) * 64 + h) * 16 + w4];
      }
      // store phase for row r (hp = h0r+r+1): identity-order 16B chunks over
      // the contiguous 4224B row; swizzle inverted on the LDS-read side.
      int hp = h0r + r + 1;
      char* dst = (char*)(dstbase + (size_t)hp * 2112);
      const float (*tcur)[33] = sm.t2[r & 1];
      for (int m = tid; m < 264; m += 256) {
        int wp = m >> 2, gp = m & 3;
        bf16x8 rv;
        if (wp == 0 || wp == 65) {
#pragma unroll
          for (int j = 0; j < 8; j++) rv[j] = (__bf16)0.f;
        } else {
          int gsrc = gp ^ ((wp >> 1) & 3);
          const float* s = &tcur[wp - 1][gsrc * 8];
#pragma unroll
          for (int j = 0; j < 8; j++) rv[j] = (__bf16)s[j];
        }
        *(bf16x8*)(dst + m * 16) = rv;
      }
      // stage next row into the other buffer
      if (r < 7) {
        float (*tn)[33] = sm.t2[(r + 1) & 1];
        tn[w4 * 4 + 0][c0] = n0.x; tn[w4 * 4 + 1][c0] = n0.y;
        tn[w4 * 4 + 2][c0] = n0.z; tn[w4 * 4 + 3][c0] = n0.w;
        tn[w4 * 4 + 0][c0 + 16] = n1.x; tn[w4 * 4 + 1][c0 + 16] = n1.y;
        tn[w4 * 4 + 2][c0 + 16] = n1.z; tn[w4 * 4 + 3][c0 + 16] = n1.w;
      }
      __syncthreads();
    }
    // edge padding rows hp=0 (hg==0) / hp=65 (hg==7)
    if (hg == 0 || hg == 7) {
      int hp = (hg == 0) ? 0 : 65;
      float4* dz = (float4*)(dstbase + (size_t)hp * 2112);
      float4 z4 = {0.f, 0.f, 0.f, 0.f};
      for (int i = tid; i < 264; i += 256) dz[i] = z4;
    }
  }
}

// ---------------- kernel 3: MFMA conv — 4-h blocks, counted-vmcnt ch barrier (T4) ----------------
__global__ __launch_bounds__(512, 2) void conv_kernel(const __bf16* __restrict__ qT,
                                                      const __bf16* __restrict__ wf,
                                                      float* __restrict__ out) {
  __shared__ __align__(16) __bf16 Qlds[2][6 * 66 * 32];  // 2 x 25,344 B = 50.7 KB
  const int tid = threadIdx.x;
  const int lane = tid & 63;
  const int wv = tid >> 6;        // 0..7
  const int wm = wv >> 2;         // o half (0/1)
  const int wn = wv & 3;          // h row within block (0..3)
  const int l15 = lane & 15, qd = lane >> 4;

  const int bid = blockIdx.x;
  const int b = bid & 7;          // XCD swizzle: b's wf+qT (~3.4MB) pinned to one XCD L2
  const int rem = bid >> 3;       // 0..31
  const int o0 = (rem >> 4) * 128;
  const int hq = (rem & 15) * 4;  // 4 output rows per block

  f32x4 acc[4][4];
  {
    f32x4 z = {0.f, 0.f, 0.f, 0.f};
#pragma unroll
    for (int i = 0; i < 4; i++)
#pragma unroll
      for (int j = 0; j < 4; j++) acc[i][j] = z;
  }

  const char* qT_b = (const char*)qT + (size_t)b * 8 * 66 * 66 * 32 * 2;
  // A-fragment base, identity-order layout: lane reads 16 B at
  //   (o0+wm*64)*64 + lane*16  (+ mi*1024 per mi, + (tap*8+ch)*16384 per step)
  const char* abase = (const char*)wf + (size_t)b * 9 * 8 * 16384 +
                      (size_t)(o0 + wm * 64) * 64 + (size_t)lane * 16;
  // 3-phase A register rotation: tap t consumes areg[t%3], issues A(t+2).
  bf16x8 areg[3][4];

  // ---- prologue: stage Q(ch=0) rows hq..hq+5 -> Qlds[0]; load A(0), A(1)
  {
    const char* qsrc = qT_b + ((size_t)hq) * 66 * 32 * 2;
    for (int i = tid; i < 1584; i += 512) {
      int ub = i - lane;
      __builtin_amdgcn_global_load_lds((const AS1 void*)(qsrc + ((size_t)i << 4)),
                                       (AS3 void*)((char*)Qlds[0] + ((size_t)ub << 4)),
                                       16, 0, 0);
    }
#pragma unroll
    for (int mi = 0; mi < 4; mi++) {
      areg[0][mi] = *(const bf16x8*)(abase + mi * 1024);                      // (tap0,ch0)
      areg[1][mi] = *(const bf16x8*)(abase + ((size_t)8 << 14) + mi * 1024);  // (tap1,ch0)
    }
    // drain Q0 (older than the 8 A loads); keep A(0),A(1) in flight
    asm volatile("s_waitcnt vmcnt(8) lgkmcnt(0)" ::: "memory");
    __builtin_amdgcn_sched_barrier(0);
    __builtin_amdgcn_s_barrier();
    __builtin_amdgcn_sched_barrier(0);
  }

#pragma unroll 1
  for (int ch = 0; ch < 8; ch++) {
    const char* Qb = (const char*)Qlds[ch & 1];
    const char* qsrc_n = qT_b + ((size_t)(ch + 1) * 66 + hq) * 66 * 32 * 2;
    char* qdst_n = (char*)Qlds[(ch + 1) & 1];
#pragma unroll
    for (int tap = 0; tap < 9; tap++) {
      // 1) issue A(t+2) first (ahead of Q issues this tap)
      {
        int tapn = (tap + 2 >= 9) ? tap - 7 : tap + 2;
        int chn = (tap + 2 >= 9) ? ch + 1 : ch;  // chn==8 on last ch: in-bounds garbage, unused
        size_t aoff = ((size_t)(tapn * 8 + chn)) << 14;
#pragma unroll
        for (int mi = 0; mi < 4; mi++)
          areg[(tap + 2) % 3][mi] = *(const bf16x8*)(abase + aoff + mi * 1024);
      }
      // 2) Q staging for ch+1, two halves at tap0/tap1
      if (ch < 7) {
        if (tap == 0) {
          for (int i = tid; i < 792; i += 512) {
            int ub = i - lane;
            __builtin_amdgcn_global_load_lds((const AS1 void*)(qsrc_n + ((size_t)i << 4)),
                                             (AS3 void*)(qdst_n + ((size_t)ub << 4)),
                                             16, 0, 0);
          }
        } else if (tap == 1) {
          for (int i = 792 + tid; i < 1584; i += 512) {
            int ub = i - lane;
            __builtin_amdgcn_global_load_lds((const AS1 void*)(qsrc_n + ((size_t)i << 4)),
                                             (AS3 void*)(qdst_n + ((size_t)ub << 4)),
                                             16, 0, 0);
          }
        }
      }
      // 3) compute with areg[tap%3]
      const int dh = tap / 3, dw = tap - dh * 3;
      const int r = wn + dh;  // 0..5
#pragma unroll
      for (int ni = 0; ni < 4; ni++) {
        int wp = ni * 16 + l15 + dw;  // 0..65
        int g = (qd ^ ((wp >> 1) & 3)) << 3;
        bf16x8 bfv = *(const bf16x8*)(Qb + ((r * 66 + wp) * 32 + g) * 2);
#pragma unroll
        for (int mi = 0; mi < 4; mi++)
          acc[mi][ni] = __builtin_amdgcn_mfma_f32_16x16x32_bf16(
              areg[tap % 3][mi], bfv, acc[mi][ni], 0, 0, 0);
      }
    }
    // ---- counted-vmcnt ch barrier (T4): the 8 newest VMEM ops are the two
    // next-ch A-prefetch batches; everything older (this ch's Q DMA) drains.
    // Per-wave drain + barrier => Qlds[(ch+1)&1] complete for all waves.
    asm volatile("s_waitcnt vmcnt(8) lgkmcnt(0)" ::: "memory");
    __builtin_amdgcn_sched_barrier(0);
    __builtin_amdgcn_s_barrier();
    __builtin_amdgcn_sched_barrier(0);
  }

  // epilogue: C/D layout col = lane&15 (w), row = qd*4+rr (o)
  const int hh = hq + wn;
#pragma unroll
  for (int mi = 0; mi < 4; mi++) {
    int o = o0 + wm * 64 + mi * 16 + qd * 4;
#pragma unroll
    for (int ni = 0; ni < 4; ni++) {
      int w = ni * 16 + l15;
#pragma unroll
      for (int rr = 0; rr < 4; rr++)
        out[(((size_t)b * 256 + (o + rr)) * 64 + hh) * 64 + w] = acc[mi][ni][rr];
    }
  }
}

extern "C" void kernel_launch(void* const* d_in, const int* in_sizes, int n_in,
                              void* d_out, int out_size, void* d_ws, size_t ws_size,
                              hipStream_t stream) {
  (void)in_sizes; (void)n_in; (void)out_size; (void)ws_size;
  const float* q = (const float*)d_in[0];
  const float* y = (const float*)d_in[1];
  const float* experts = (const float*)d_in[2];
  const float* gate_w = (const float*)d_in[3];
  const float* gate_b = (const float*)d_in[4];
  float* out = (float*)d_out;

  char* ws = (char*)d_ws;
  float* yctx = (float*)ws;                         // 8 KB
  __bf16* wf = (__bf16*)(ws + 16384);               // 9,437,184 B
  __bf16* qT = (__bf16*)(ws + 16384 + 9437184);     // 17,842,176 B

  yctx_kernel<<<2048, 256, 0, stream>>>(y, yctx);
  prep_kernel<<<256 + 512, 256, 0, stream>>>(q, experts, yctx, gate_w, gate_b, qT, wf);
  conv_kernel<<<256, 512, 0, stream>>>(qT, wf, out);
}